// Round 1
// baseline (228.693 us; speedup 1.0000x reference)
//
#include <hip/hip_runtime.h>
#include <math.h>

#define N_STEPS 256
#define DENSITY_SCALE 10.0f
#define REF_EPS 1e-8f

// 4 threads cooperate on one ray; thread `sub` handles steps sub, sub+4, ...
// Grid is 256^3 fp32: index (z<<16)+(y<<8)+x.
__global__ __launch_bounds__(256) void transmittance_kernel(
    const float* __restrict__ rays,   // [N,6] (origin xyz, dir xyz)
    const float* __restrict__ grid,   // [256,256,256]
    float* __restrict__ out,          // [N]
    int n_rays)
{
    int gid = blockIdx.x * blockDim.x + threadIdx.x;
    int ray = gid >> 2;
    int sub = gid & 3;
    if (ray >= n_rays) return;

    const float* r = rays + ray * 6;
    float ox = r[0], oy = r[1], oz = r[2];
    float dx = r[3], dy = r[4], dz = r[5];

    // normalize direction (matches jnp.linalg.norm + EPS)
    float nrm = sqrtf(dx*dx + dy*dy + dz*dz) + REF_EPS;
    float inv_n = 1.0f / nrm;
    dx *= inv_n; dy *= inv_n; dz *= inv_n;

    // inv_d with reference semantics: where(|d|<EPS, sign(d)*EPS+EPS, d)
    auto safe_inv = [](float d) -> float {
        float denom = d;
        if (fabsf(d) < REF_EPS) {
            float s = (d > 0.0f) ? 1.0f : ((d < 0.0f) ? -1.0f : 0.0f);
            denom = s * REF_EPS + REF_EPS;   // may be 0 -> inf, matches jnp
        }
        return 1.0f / denom;
    };
    float ix = safe_inv(dx), iy = safe_inv(dy), iz = safe_inv(dz);

    float tax = (-1.0f - ox) * ix, tbx = (1.0f - ox) * ix;
    float tay = (-1.0f - oy) * iy, tby = (1.0f - oy) * iy;
    float taz = (-1.0f - oz) * iz, tbz = (1.0f - oz) * iz;

    float tmin = fmaxf(fmaxf(fminf(tax, tbx), fminf(tay, tby)), fminf(taz, tbz));
    float tmax = fminf(fminf(fmaxf(tax, tbx), fmaxf(tay, tby)), fmaxf(taz, tbz));
    tmin = fmaxf(tmin, 0.0f);
    bool valid = tmax > tmin;

    float result = 1.0f;
    float seg = valid ? (tmax - tmin) : 0.0f;
    float sum = 0.0f;

    if (valid) {
        #pragma unroll 4
        for (int i = sub; i < N_STEPS; i += 4) {
            // frac is bit-exact vs (arange+0.5)/256: (i+0.5) exact, *2^-8 exact
            float frac = ((float)i + 0.5f) * (1.0f / (float)N_STEPS);
            float t = fmaf(seg, frac, tmin);
            float px = fmaf(t, dx, ox);
            float py = fmaf(t, dy, oy);
            float pz = fmaf(t, dz, oz);
            float gx = (px + 1.0f) * (0.5f * 255.0f);
            float gy = (py + 1.0f) * (0.5f * 255.0f);
            float gz = (pz + 1.0f) * (0.5f * 255.0f);

            float fx0 = floorf(gx), fy0 = floorf(gy), fz0 = floorf(gz);
            int x0 = (int)fminf(fmaxf(fx0, 0.0f), 254.0f);
            int y0 = (int)fminf(fmaxf(fy0, 0.0f), 254.0f);
            int z0 = (int)fminf(fmaxf(fz0, 0.0f), 254.0f);
            float fx = fminf(fmaxf(gx - (float)x0, 0.0f), 1.0f);
            float fy = fminf(fmaxf(gy - (float)y0, 0.0f), 1.0f);
            float fz = fminf(fmaxf(gz - (float)z0, 0.0f), 1.0f);

            const float* p0 = grid + ((z0 << 16) + (y0 << 8) + x0);
            const float* p1 = p0 + 65536;
            float c000 = p0[0],   c001 = p0[1];
            float c010 = p0[256], c011 = p0[257];
            float c100 = p1[0],   c101 = p1[1];
            float c110 = p1[256], c111 = p1[257];

            float omfx = 1.0f - fx;
            float c00 = c000 * omfx + c001 * fx;
            float c01 = c010 * omfx + c011 * fx;
            float c10 = c100 * omfx + c101 * fx;
            float c11 = c110 * omfx + c111 * fx;
            float omfy = 1.0f - fy;
            float c0 = c00 * omfy + c01 * fy;
            float c1 = c10 * omfy + c11 * fy;
            sum += c0 * (1.0f - fz) + c1 * fz;
        }
    }

    // reduce the 4 sub-thread partial sums (lanes 4r..4r+3 hold one ray)
    sum += __shfl_xor(sum, 1);
    sum += __shfl_xor(sum, 2);

    if (valid) {
        float dt = seg * (1.0f / (float)N_STEPS);
        float tau = DENSITY_SCALE * sum * dt;
        result = expf(-tau);
    }

    if (sub == 0) out[ray] = result;
}

extern "C" void kernel_launch(void* const* d_in, const int* in_sizes, int n_in,
                              void* d_out, int out_size, void* d_ws, size_t ws_size,
                              hipStream_t stream) {
    const float* rays = (const float*)d_in[0];   // [65536, 6] fp32
    const float* grid = (const float*)d_in[1];   // [256,256,256] fp32
    float* out = (float*)d_out;                  // [65536] fp32
    int n_rays = in_sizes[0] / 6;
    int total_threads = n_rays * 4;
    dim3 block(256);
    dim3 grid_dim((total_threads + 255) / 256);
    transmittance_kernel<<<grid_dim, block, 0, stream>>>(rays, grid, out, n_rays);
}

// Round 2
// 224.645 us; speedup vs baseline: 1.0180x; 1.0180x over previous
//
#include <hip/hip_runtime.h>
#include <hip/hip_fp16.h>
#include <math.h>
#include <stdint.h>

#define N_STEPS 256
#define DENSITY_SCALE 10.0f
#define REF_EPS 1e-8f

typedef uint32_t u32_a2 __attribute__((aligned(2)));

// ---------------- repack: fp32 grid -> fp16 grid in workspace ----------------
__global__ __launch_bounds__(256) void repack_kernel(
    const float* __restrict__ g, __half* __restrict__ gh, int n)
{
    int i = (blockIdx.x * blockDim.x + threadIdx.x) * 4;
    if (i >= n) return;
    float4 v = *(const float4*)(g + i);
    // reference clips grid to [0,1] (no-op for uniform input, but free safety)
    v.x = fminf(fmaxf(v.x, 0.0f), 1.0f);
    v.y = fminf(fmaxf(v.y, 0.0f), 1.0f);
    v.z = fminf(fmaxf(v.z, 0.0f), 1.0f);
    v.w = fminf(fmaxf(v.w, 0.0f), 1.0f);
    __half2* dst = (__half2*)(gh + i);
    dst[0] = __floats2half2_rn(v.x, v.y);
    dst[1] = __floats2half2_rn(v.z, v.w);
}

// ---------------- common ray setup ----------------
__device__ __forceinline__ float safe_inv(float d) {
    float denom = d;
    if (fabsf(d) < REF_EPS) {
        float s = (d > 0.0f) ? 1.0f : ((d < 0.0f) ? -1.0f : 0.0f);
        denom = s * REF_EPS + REF_EPS;   // may be 0 -> inf, matches jnp
    }
    return 1.0f / denom;
}

// ---------------- main kernel: fp16 grid, 8 threads per ray ----------------
__global__ __launch_bounds__(256) void transmittance_h_kernel(
    const float* __restrict__ rays,
    const __half* __restrict__ gh,    // [256,256,256] fp16
    float* __restrict__ out,
    int n_rays)
{
    int gid = blockIdx.x * blockDim.x + threadIdx.x;
    int ray = gid >> 3;
    int sub = gid & 7;
    if (ray >= n_rays) return;

    const float* r = rays + ray * 6;
    float ox = r[0], oy = r[1], oz = r[2];
    float dx = r[3], dy = r[4], dz = r[5];

    float nrm = sqrtf(dx*dx + dy*dy + dz*dz) + REF_EPS;
    float inv_n = 1.0f / nrm;
    dx *= inv_n; dy *= inv_n; dz *= inv_n;

    float ixv = safe_inv(dx), iyv = safe_inv(dy), izv = safe_inv(dz);

    float tax = (-1.0f - ox) * ixv, tbx = (1.0f - ox) * ixv;
    float tay = (-1.0f - oy) * iyv, tby = (1.0f - oy) * iyv;
    float taz = (-1.0f - oz) * izv, tbz = (1.0f - oz) * izv;

    float tmin = fmaxf(fmaxf(fminf(tax, tbx), fminf(tay, tby)), fminf(taz, tbz));
    float tmax = fminf(fminf(fmaxf(tax, tbx), fmaxf(tay, tby)), fmaxf(taz, tbz));
    tmin = fmaxf(tmin, 0.0f);
    bool valid = tmax > tmin;

    float seg = valid ? (tmax - tmin) : 0.0f;
    float sum = 0.0f;

    if (valid) {
        #pragma unroll 4
        for (int i = sub; i < N_STEPS; i += 8) {
            float frac = ((float)i + 0.5f) * (1.0f / (float)N_STEPS);
            float t = fmaf(seg, frac, tmin);
            float px = fmaf(t, dx, ox);
            float py = fmaf(t, dy, oy);
            float pz = fmaf(t, dz, oz);
            float gx = (px + 1.0f) * (0.5f * 255.0f);
            float gy = (py + 1.0f) * (0.5f * 255.0f);
            float gz = (pz + 1.0f) * (0.5f * 255.0f);

            float fx0 = floorf(gx), fy0 = floorf(gy), fz0 = floorf(gz);
            int x0 = (int)fminf(fmaxf(fx0, 0.0f), 254.0f);
            int y0 = (int)fminf(fmaxf(fy0, 0.0f), 254.0f);
            int z0 = (int)fminf(fmaxf(fz0, 0.0f), 254.0f);
            float fx = fminf(fmaxf(gx - (float)x0, 0.0f), 1.0f);
            float fy = fminf(fmaxf(gy - (float)y0, 0.0f), 1.0f);
            float fz = fminf(fmaxf(gz - (float)z0, 0.0f), 1.0f);

            const __half* p0 = gh + ((z0 << 16) + (y0 << 8) + x0);
            // each x-pair is one (possibly unaligned) dword load
            u32_a2 a00 = *(const u32_a2*)(const void*)(p0);
            u32_a2 a01 = *(const u32_a2*)(const void*)(p0 + 256);
            u32_a2 a10 = *(const u32_a2*)(const void*)(p0 + 65536);
            u32_a2 a11 = *(const u32_a2*)(const void*)(p0 + 65536 + 256);

            float2 f00 = __half22float2(*(__half2*)&a00);  // c000,c001
            float2 f01 = __half22float2(*(__half2*)&a01);  // c010,c011
            float2 f10 = __half22float2(*(__half2*)&a10);  // c100,c101
            float2 f11 = __half22float2(*(__half2*)&a11);  // c110,c111

            float omfx = 1.0f - fx;
            float c00 = f00.x * omfx + f00.y * fx;
            float c01 = f01.x * omfx + f01.y * fx;
            float c10 = f10.x * omfx + f10.y * fx;
            float c11 = f11.x * omfx + f11.y * fx;
            float omfy = 1.0f - fy;
            float c0 = c00 * omfy + c01 * fy;
            float c1 = c10 * omfy + c11 * fy;
            sum += c0 * (1.0f - fz) + c1 * fz;
        }
    }

    // reduce 8 partial sums (lanes 8r..8r+7 hold one ray)
    sum += __shfl_xor(sum, 1);
    sum += __shfl_xor(sum, 2);
    sum += __shfl_xor(sum, 4);

    if (sub == 0) {
        float result = 1.0f;
        if (valid) {
            float dt = seg * (1.0f / (float)N_STEPS);
            float tau = DENSITY_SCALE * sum * dt;
            result = expf(-tau);
        }
        out[ray] = result;
    }
}

// ---------------- fallback: fp32 grid, 4 threads per ray (round-1 kernel) ----
__global__ __launch_bounds__(256) void transmittance_kernel(
    const float* __restrict__ rays,
    const float* __restrict__ grid,
    float* __restrict__ out,
    int n_rays)
{
    int gid = blockIdx.x * blockDim.x + threadIdx.x;
    int ray = gid >> 2;
    int sub = gid & 3;
    if (ray >= n_rays) return;

    const float* r = rays + ray * 6;
    float ox = r[0], oy = r[1], oz = r[2];
    float dx = r[3], dy = r[4], dz = r[5];

    float nrm = sqrtf(dx*dx + dy*dy + dz*dz) + REF_EPS;
    float inv_n = 1.0f / nrm;
    dx *= inv_n; dy *= inv_n; dz *= inv_n;

    float ixv = safe_inv(dx), iyv = safe_inv(dy), izv = safe_inv(dz);

    float tax = (-1.0f - ox) * ixv, tbx = (1.0f - ox) * ixv;
    float tay = (-1.0f - oy) * iyv, tby = (1.0f - oy) * iyv;
    float taz = (-1.0f - oz) * izv, tbz = (1.0f - oz) * izv;

    float tmin = fmaxf(fmaxf(fminf(tax, tbx), fminf(tay, tby)), fminf(taz, tbz));
    float tmax = fminf(fminf(fmaxf(tax, tbx), fmaxf(tay, tby)), fmaxf(taz, tbz));
    tmin = fmaxf(tmin, 0.0f);
    bool valid = tmax > tmin;

    float result = 1.0f;
    float seg = valid ? (tmax - tmin) : 0.0f;
    float sum = 0.0f;

    if (valid) {
        #pragma unroll 4
        for (int i = sub; i < N_STEPS; i += 4) {
            float frac = ((float)i + 0.5f) * (1.0f / (float)N_STEPS);
            float t = fmaf(seg, frac, tmin);
            float px = fmaf(t, dx, ox);
            float py = fmaf(t, dy, oy);
            float pz = fmaf(t, dz, oz);
            float gx = (px + 1.0f) * (0.5f * 255.0f);
            float gy = (py + 1.0f) * (0.5f * 255.0f);
            float gz = (pz + 1.0f) * (0.5f * 255.0f);

            float fx0 = floorf(gx), fy0 = floorf(gy), fz0 = floorf(gz);
            int x0 = (int)fminf(fmaxf(fx0, 0.0f), 254.0f);
            int y0 = (int)fminf(fmaxf(fy0, 0.0f), 254.0f);
            int z0 = (int)fminf(fmaxf(fz0, 0.0f), 254.0f);
            float fx = fminf(fmaxf(gx - (float)x0, 0.0f), 1.0f);
            float fy = fminf(fmaxf(gy - (float)y0, 0.0f), 1.0f);
            float fz = fminf(fmaxf(gz - (float)z0, 0.0f), 1.0f);

            const float* p0 = grid + ((z0 << 16) + (y0 << 8) + x0);
            const float* p1 = p0 + 65536;
            float c000 = p0[0],   c001 = p0[1];
            float c010 = p0[256], c011 = p0[257];
            float c100 = p1[0],   c101 = p1[1];
            float c110 = p1[256], c111 = p1[257];

            float omfx = 1.0f - fx;
            float c00 = c000 * omfx + c001 * fx;
            float c01 = c010 * omfx + c011 * fx;
            float c10 = c100 * omfx + c101 * fx;
            float c11 = c110 * omfx + c111 * fx;
            float omfy = 1.0f - fy;
            float c0 = c00 * omfy + c01 * fy;
            float c1 = c10 * omfy + c11 * fy;
            sum += c0 * (1.0f - fz) + c1 * fz;
        }
    }

    sum += __shfl_xor(sum, 1);
    sum += __shfl_xor(sum, 2);

    if (valid) {
        float dt = seg * (1.0f / (float)N_STEPS);
        float tau = DENSITY_SCALE * sum * dt;
        result = expf(-tau);
    }

    if (sub == 0) out[ray] = result;
}

extern "C" void kernel_launch(void* const* d_in, const int* in_sizes, int n_in,
                              void* d_out, int out_size, void* d_ws, size_t ws_size,
                              hipStream_t stream) {
    const float* rays = (const float*)d_in[0];   // [65536, 6] fp32
    const float* grid = (const float*)d_in[1];   // [256,256,256] fp32
    float* out = (float*)d_out;
    int n_rays = in_sizes[0] / 6;
    int n_grid = in_sizes[1];                    // 16777216

    size_t need = (size_t)n_grid * sizeof(__half);
    if (ws_size >= need) {
        __half* gh = (__half*)d_ws;
        int rp_threads = n_grid / 4;
        repack_kernel<<<(rp_threads + 255) / 256, 256, 0, stream>>>(grid, gh, n_grid);
        int total_threads = n_rays * 8;
        transmittance_h_kernel<<<(total_threads + 255) / 256, 256, 0, stream>>>(
            rays, gh, out, n_rays);
    } else {
        int total_threads = n_rays * 4;
        transmittance_kernel<<<(total_threads + 255) / 256, 256, 0, stream>>>(
            rays, grid, out, n_rays);
    }
}

// Round 3
// 212.282 us; speedup vs baseline: 1.0773x; 1.0582x over previous
//
#include <hip/hip_runtime.h>
#include <hip/hip_fp16.h>
#include <math.h>
#include <stdint.h>

#define N_STEPS 256
#define DENSITY_SCALE 10.0f
#define REF_EPS 1e-8f

typedef uint32_t u32_a2 __attribute__((aligned(2)));
struct __attribute__((packed, aligned(4))) HPair4 { __half2 lo; __half2 hi; };

__device__ __forceinline__ float clip01(float v) {
    return fminf(fmaxf(v, 0.0f), 1.0f);
}

__device__ __forceinline__ float safe_inv(float d) {
    float denom = d;
    if (fabsf(d) < REF_EPS) {
        float s = (d > 0.0f) ? 1.0f : ((d < 0.0f) ? -1.0f : 0.0f);
        denom = s * REF_EPS + REF_EPS;   // may be 0 -> inf, matches jnp
    }
    return 1.0f / denom;
}

// ---------------- repack: gh2[z][y][x] = half2(g[z][y][x], g[z][y+1][x]) ----
// One thread per 4 consecutive x. Also zeroes the compaction counter.
__global__ __launch_bounds__(256) void repack_ypair_kernel(
    const float* __restrict__ g, __half2* __restrict__ gh2, int* __restrict__ counter)
{
    if (blockIdx.x == 0 && threadIdx.x == 0) *counter = 0;
    int t = blockIdx.x * blockDim.x + threadIdx.x;     // [0, 256*256*64)
    int x4 = (t & 63) << 2;
    int zy = t >> 6;                                   // (z<<8)+y
    int y  = zy & 255;
    int base  = (zy << 8) + x4;                        // (z<<16)+(y<<8)+x4
    int zyp   = (y == 255) ? zy : (zy + 1);            // clamp row y+1 (unused values)
    int basep = (zyp << 8) + x4;
    float4 v0 = *(const float4*)(g + base);
    float4 v1 = *(const float4*)(g + basep);
    __half2* dst = gh2 + base;
    dst[0] = __floats2half2_rn(clip01(v0.x), clip01(v1.x));
    dst[1] = __floats2half2_rn(clip01(v0.y), clip01(v1.y));
    dst[2] = __floats2half2_rn(clip01(v0.z), clip01(v1.z));
    dst[3] = __floats2half2_rn(clip01(v0.w), clip01(v1.w));
}

// ---------------- setup: slab test + wave-ballot compaction ----------------
// compactF[idx*8] = {ox,oy,oz,dx,dy,dz,tmin,seg}; compactI[idx] = ray id.
__global__ __launch_bounds__(256) void setup_kernel(
    const float* __restrict__ rays, float* __restrict__ out,
    float* __restrict__ compactF, int* __restrict__ compactI,
    int* __restrict__ counter, int n_rays)
{
    int ray = blockIdx.x * blockDim.x + threadIdx.x;
    bool valid = false;
    float ox = 0, oy = 0, oz = 0, dx = 0, dy = 0, dz = 0, tmin = 0, seg = 0;

    if (ray < n_rays) {
        const float* r = rays + ray * 6;
        ox = r[0]; oy = r[1]; oz = r[2];
        dx = r[3]; dy = r[4]; dz = r[5];
        float nrm = sqrtf(dx*dx + dy*dy + dz*dz) + REF_EPS;
        float inv_n = 1.0f / nrm;
        dx *= inv_n; dy *= inv_n; dz *= inv_n;
        float ixv = safe_inv(dx), iyv = safe_inv(dy), izv = safe_inv(dz);
        float tax = (-1.0f - ox) * ixv, tbx = (1.0f - ox) * ixv;
        float tay = (-1.0f - oy) * iyv, tby = (1.0f - oy) * iyv;
        float taz = (-1.0f - oz) * izv, tbz = (1.0f - oz) * izv;
        tmin = fmaxf(fmaxf(fminf(tax, tbx), fminf(tay, tby)), fminf(taz, tbz));
        float tmax = fminf(fminf(fmaxf(tax, tbx), fmaxf(tay, tby)), fmaxf(taz, tbz));
        tmin = fmaxf(tmin, 0.0f);
        valid = tmax > tmin;
        seg = valid ? (tmax - tmin) : 0.0f;
    }

    unsigned long long mask = __ballot(valid);
    int lane = threadIdx.x & 63;
    int nbefore = __popcll(mask & ((1ull << lane) - 1ull));
    int total = __popcll(mask);
    int base = 0;
    if (lane == 0) base = atomicAdd(counter, total);
    base = __shfl(base, 0);

    if (valid) {
        int idx = base + nbefore;
        float4* dst = (float4*)(compactF + (size_t)idx * 8);
        dst[0] = make_float4(ox, oy, oz, dx);
        dst[1] = make_float4(dy, dz, tmin, seg);
        compactI[idx] = ray;
    } else if (ray < n_rays) {
        out[ray] = 1.0f;
    }
}

// ---------------- march: 8 threads per valid ray, y-pair grid ----------------
__global__ __launch_bounds__(256) void march_kernel(
    const float* __restrict__ compactF, const int* __restrict__ compactI,
    const int* __restrict__ counter, const __half2* __restrict__ gh2,
    float* __restrict__ out)
{
    int gid = blockIdx.x * blockDim.x + threadIdx.x;
    int ray = gid >> 3;
    int sub = gid & 7;
    int nvalid = *counter;
    if (ray >= nvalid) return;

    const float4* c = (const float4*)(compactF + (size_t)ray * 8);
    float4 c0 = c[0], c1 = c[1];
    float ox = c0.x, oy = c0.y, oz = c0.z;
    float dx = c0.w, dy = c1.x, dz = c1.y;
    float tmin = c1.z, seg = c1.w;

    float sum = 0.0f;
    #pragma unroll 4
    for (int i = sub; i < N_STEPS; i += 8) {
        float frac = ((float)i + 0.5f) * (1.0f / (float)N_STEPS);
        float t = fmaf(seg, frac, tmin);
        float px = fmaf(t, dx, ox);
        float py = fmaf(t, dy, oy);
        float pz = fmaf(t, dz, oz);
        float gx = (px + 1.0f) * (0.5f * 255.0f);
        float gy = (py + 1.0f) * (0.5f * 255.0f);
        float gz = (pz + 1.0f) * (0.5f * 255.0f);

        float fx0 = floorf(gx), fy0 = floorf(gy), fz0 = floorf(gz);
        int x0 = (int)fminf(fmaxf(fx0, 0.0f), 254.0f);
        int y0 = (int)fminf(fmaxf(fy0, 0.0f), 254.0f);
        int z0 = (int)fminf(fmaxf(fz0, 0.0f), 254.0f);
        float fx = fminf(fmaxf(gx - (float)x0, 0.0f), 1.0f);
        float fy = fminf(fmaxf(gy - (float)y0, 0.0f), 1.0f);
        float fz = fminf(fmaxf(gz - (float)z0, 0.0f), 1.0f);

        int vidx = (z0 << 16) + (y0 << 8) + x0;
        HPair4 v0 = *(const HPair4*)(const void*)(gh2 + vidx);           // (c000,c010),(c001,c011)
        HPair4 v1 = *(const HPair4*)(const void*)(gh2 + vidx + 65536);   // (c100,c110),(c101,c111)

        float2 a0 = __half22float2(v0.lo);   // c000, c010
        float2 a1 = __half22float2(v0.hi);   // c001, c011
        float2 b0 = __half22float2(v1.lo);   // c100, c110
        float2 b1 = __half22float2(v1.hi);   // c101, c111

        float omfx = 1.0f - fx;
        float c00 = a0.x * omfx + a1.x * fx;
        float c01 = a0.y * omfx + a1.y * fx;
        float c10 = b0.x * omfx + b1.x * fx;
        float c11 = b0.y * omfx + b1.y * fx;
        float omfy = 1.0f - fy;
        float cc0 = c00 * omfy + c01 * fy;
        float cc1 = c10 * omfy + c11 * fy;
        sum += cc0 * (1.0f - fz) + cc1 * fz;
    }

    sum += __shfl_xor(sum, 1);
    sum += __shfl_xor(sum, 2);
    sum += __shfl_xor(sum, 4);

    if (sub == 0) {
        float dt = seg * (1.0f / (float)N_STEPS);
        float tau = DENSITY_SCALE * sum * dt;
        out[compactI[ray]] = expf(-tau);
    }
}

// ---------------- fallback: fp16 flat grid, 8 threads per ray (round-2) -----
__global__ __launch_bounds__(256) void repack_kernel(
    const float* __restrict__ g, __half* __restrict__ gh, int n)
{
    int i = (blockIdx.x * blockDim.x + threadIdx.x) * 4;
    if (i >= n) return;
    float4 v = *(const float4*)(g + i);
    __half2* dst = (__half2*)(gh + i);
    dst[0] = __floats2half2_rn(clip01(v.x), clip01(v.y));
    dst[1] = __floats2half2_rn(clip01(v.z), clip01(v.w));
}

__global__ __launch_bounds__(256) void transmittance_h_kernel(
    const float* __restrict__ rays, const __half* __restrict__ gh,
    float* __restrict__ out, int n_rays)
{
    int gid = blockIdx.x * blockDim.x + threadIdx.x;
    int ray = gid >> 3;
    int sub = gid & 7;
    if (ray >= n_rays) return;

    const float* r = rays + ray * 6;
    float ox = r[0], oy = r[1], oz = r[2];
    float dx = r[3], dy = r[4], dz = r[5];
    float nrm = sqrtf(dx*dx + dy*dy + dz*dz) + REF_EPS;
    float inv_n = 1.0f / nrm;
    dx *= inv_n; dy *= inv_n; dz *= inv_n;
    float ixv = safe_inv(dx), iyv = safe_inv(dy), izv = safe_inv(dz);
    float tax = (-1.0f - ox) * ixv, tbx = (1.0f - ox) * ixv;
    float tay = (-1.0f - oy) * iyv, tby = (1.0f - oy) * iyv;
    float taz = (-1.0f - oz) * izv, tbz = (1.0f - oz) * izv;
    float tmin = fmaxf(fmaxf(fminf(tax, tbx), fminf(tay, tby)), fminf(taz, tbz));
    float tmax = fminf(fminf(fmaxf(tax, tbx), fmaxf(tay, tby)), fmaxf(taz, tbz));
    tmin = fmaxf(tmin, 0.0f);
    bool valid = tmax > tmin;
    float seg = valid ? (tmax - tmin) : 0.0f;
    float sum = 0.0f;

    if (valid) {
        #pragma unroll 4
        for (int i = sub; i < N_STEPS; i += 8) {
            float frac = ((float)i + 0.5f) * (1.0f / (float)N_STEPS);
            float t = fmaf(seg, frac, tmin);
            float px = fmaf(t, dx, ox);
            float py = fmaf(t, dy, oy);
            float pz = fmaf(t, dz, oz);
            float gx = (px + 1.0f) * (0.5f * 255.0f);
            float gy = (py + 1.0f) * (0.5f * 255.0f);
            float gz = (pz + 1.0f) * (0.5f * 255.0f);
            float fx0 = floorf(gx), fy0 = floorf(gy), fz0 = floorf(gz);
            int x0 = (int)fminf(fmaxf(fx0, 0.0f), 254.0f);
            int y0 = (int)fminf(fmaxf(fy0, 0.0f), 254.0f);
            int z0 = (int)fminf(fmaxf(fz0, 0.0f), 254.0f);
            float fx = fminf(fmaxf(gx - (float)x0, 0.0f), 1.0f);
            float fy = fminf(fmaxf(gy - (float)y0, 0.0f), 1.0f);
            float fz = fminf(fmaxf(gz - (float)z0, 0.0f), 1.0f);
            const __half* p0 = gh + ((z0 << 16) + (y0 << 8) + x0);
            u32_a2 a00 = *(const u32_a2*)(const void*)(p0);
            u32_a2 a01 = *(const u32_a2*)(const void*)(p0 + 256);
            u32_a2 a10 = *(const u32_a2*)(const void*)(p0 + 65536);
            u32_a2 a11 = *(const u32_a2*)(const void*)(p0 + 65536 + 256);
            float2 f00 = __half22float2(*(__half2*)&a00);
            float2 f01 = __half22float2(*(__half2*)&a01);
            float2 f10 = __half22float2(*(__half2*)&a10);
            float2 f11 = __half22float2(*(__half2*)&a11);
            float omfx = 1.0f - fx;
            float c00 = f00.x * omfx + f00.y * fx;
            float c01 = f01.x * omfx + f01.y * fx;
            float c10 = f10.x * omfx + f10.y * fx;
            float c11 = f11.x * omfx + f11.y * fx;
            float omfy = 1.0f - fy;
            float cc0 = c00 * omfy + c01 * fy;
            float cc1 = c10 * omfy + c11 * fy;
            sum += cc0 * (1.0f - fz) + cc1 * fz;
        }
    }

    sum += __shfl_xor(sum, 1);
    sum += __shfl_xor(sum, 2);
    sum += __shfl_xor(sum, 4);

    if (sub == 0) {
        float result = 1.0f;
        if (valid) {
            float dt = seg * (1.0f / (float)N_STEPS);
            float tau = DENSITY_SCALE * sum * dt;
            result = expf(-tau);
        }
        out[ray] = result;
    }
}

// ---------------- fallback: fp32 grid, 4 threads per ray (round-1) ----------
__global__ __launch_bounds__(256) void transmittance_kernel(
    const float* __restrict__ rays, const float* __restrict__ grid,
    float* __restrict__ out, int n_rays)
{
    int gid = blockIdx.x * blockDim.x + threadIdx.x;
    int ray = gid >> 2;
    int sub = gid & 3;
    if (ray >= n_rays) return;
    const float* r = rays + ray * 6;
    float ox = r[0], oy = r[1], oz = r[2];
    float dx = r[3], dy = r[4], dz = r[5];
    float nrm = sqrtf(dx*dx + dy*dy + dz*dz) + REF_EPS;
    float inv_n = 1.0f / nrm;
    dx *= inv_n; dy *= inv_n; dz *= inv_n;
    float ixv = safe_inv(dx), iyv = safe_inv(dy), izv = safe_inv(dz);
    float tax = (-1.0f - ox) * ixv, tbx = (1.0f - ox) * ixv;
    float tay = (-1.0f - oy) * iyv, tby = (1.0f - oy) * iyv;
    float taz = (-1.0f - oz) * izv, tbz = (1.0f - oz) * izv;
    float tmin = fmaxf(fmaxf(fminf(tax, tbx), fminf(tay, tby)), fminf(taz, tbz));
    float tmax = fminf(fminf(fmaxf(tax, tbx), fmaxf(tay, tby)), fmaxf(taz, tbz));
    tmin = fmaxf(tmin, 0.0f);
    bool valid = tmax > tmin;
    float result = 1.0f;
    float seg = valid ? (tmax - tmin) : 0.0f;
    float sum = 0.0f;
    if (valid) {
        #pragma unroll 4
        for (int i = sub; i < N_STEPS; i += 4) {
            float frac = ((float)i + 0.5f) * (1.0f / (float)N_STEPS);
            float t = fmaf(seg, frac, tmin);
            float px = fmaf(t, dx, ox);
            float py = fmaf(t, dy, oy);
            float pz = fmaf(t, dz, oz);
            float gx = (px + 1.0f) * (0.5f * 255.0f);
            float gy = (py + 1.0f) * (0.5f * 255.0f);
            float gz = (pz + 1.0f) * (0.5f * 255.0f);
            float fx0 = floorf(gx), fy0 = floorf(gy), fz0 = floorf(gz);
            int x0 = (int)fminf(fmaxf(fx0, 0.0f), 254.0f);
            int y0 = (int)fminf(fmaxf(fy0, 0.0f), 254.0f);
            int z0 = (int)fminf(fmaxf(fz0, 0.0f), 254.0f);
            float fx = fminf(fmaxf(gx - (float)x0, 0.0f), 1.0f);
            float fy = fminf(fmaxf(gy - (float)y0, 0.0f), 1.0f);
            float fz = fminf(fmaxf(gz - (float)z0, 0.0f), 1.0f);
            const float* p0 = grid + ((z0 << 16) + (y0 << 8) + x0);
            const float* p1 = p0 + 65536;
            float c000 = p0[0],   c001 = p0[1];
            float c010 = p0[256], c011 = p0[257];
            float c100 = p1[0],   c101 = p1[1];
            float c110 = p1[256], c111 = p1[257];
            float omfx = 1.0f - fx;
            float c00 = c000 * omfx + c001 * fx;
            float c01 = c010 * omfx + c011 * fx;
            float c10 = c100 * omfx + c101 * fx;
            float c11 = c110 * omfx + c111 * fx;
            float omfy = 1.0f - fy;
            float cc0 = c00 * omfy + c01 * fy;
            float cc1 = c10 * omfy + c11 * fy;
            sum += cc0 * (1.0f - fz) + cc1 * fz;
        }
    }
    sum += __shfl_xor(sum, 1);
    sum += __shfl_xor(sum, 2);
    if (valid) {
        float dt = seg * (1.0f / (float)N_STEPS);
        float tau = DENSITY_SCALE * sum * dt;
        result = expf(-tau);
    }
    if (sub == 0) out[ray] = result;
}

extern "C" void kernel_launch(void* const* d_in, const int* in_sizes, int n_in,
                              void* d_out, int out_size, void* d_ws, size_t ws_size,
                              hipStream_t stream) {
    const float* rays = (const float*)d_in[0];   // [65536, 6] fp32
    const float* grid = (const float*)d_in[1];   // [256,256,256] fp32
    float* out = (float*)d_out;
    int n_rays = in_sizes[0] / 6;
    int n_grid = in_sizes[1];                    // 16777216

    const size_t GH2_BYTES   = (size_t)n_grid * 4;          // 64 MB y-pair grid
    const size_t CF_BYTES    = (size_t)n_rays * 8 * 4;      // compact floats
    const size_t CI_BYTES    = (size_t)n_rays * 4;          // compact ids
    const size_t need_full   = GH2_BYTES + CF_BYTES + CI_BYTES + 256;
    const size_t need_half   = (size_t)n_grid * 2;          // 32 MB fp16 grid

    if (ws_size >= need_full) {
        __half2* gh2     = (__half2*)d_ws;
        float*   compactF = (float*)((char*)d_ws + GH2_BYTES);
        int*     compactI = (int*)((char*)d_ws + GH2_BYTES + CF_BYTES);
        int*     counter  = (int*)((char*)d_ws + GH2_BYTES + CF_BYTES + CI_BYTES);

        int rp_threads = n_grid / 4;
        repack_ypair_kernel<<<(rp_threads + 255) / 256, 256, 0, stream>>>(grid, gh2, counter);
        setup_kernel<<<(n_rays + 255) / 256, 256, 0, stream>>>(
            rays, out, compactF, compactI, counter, n_rays);
        int total_threads = n_rays * 8;   // worst case: all rays valid
        march_kernel<<<(total_threads + 255) / 256, 256, 0, stream>>>(
            compactF, compactI, counter, gh2, out);
    } else if (ws_size >= need_half) {
        __half* gh = (__half*)d_ws;
        int rp_threads = n_grid / 4;
        repack_kernel<<<(rp_threads + 255) / 256, 256, 0, stream>>>(grid, gh, n_grid);
        int total_threads = n_rays * 8;
        transmittance_h_kernel<<<(total_threads + 255) / 256, 256, 0, stream>>>(
            rays, gh, out, n_rays);
    } else {
        int total_threads = n_rays * 4;
        transmittance_kernel<<<(total_threads + 255) / 256, 256, 0, stream>>>(
            rays, grid, out, n_rays);
    }
}

// Round 4
// 179.575 us; speedup vs baseline: 1.2735x; 1.1821x over previous
//
#include <hip/hip_runtime.h>
#include <hip/hip_fp16.h>
#include <math.h>
#include <stdint.h>

#define N_STEPS 256
#define DENSITY_SCALE 10.0f
#define REF_EPS 1e-8f

typedef uint32_t u32_a2 __attribute__((aligned(2)));
typedef uint2 uint2_a4 __attribute__((aligned(4)));

__device__ __forceinline__ float clip01(float v) {
    return fminf(fmaxf(v, 0.0f), 1.0f);
}

__device__ __forceinline__ float safe_inv(float d) {
    float denom = d;
    if (fabsf(d) < REF_EPS) {
        float s = (d > 0.0f) ? 1.0f : ((d < 0.0f) ? -1.0f : 0.0f);
        denom = s * REF_EPS + REF_EPS;   // may be 0 -> inf, matches jnp
    }
    return 1.0f / denom;
}

__device__ __forceinline__ uint32_t q255(float v) {
    return (uint32_t)__float2int_rn(clip01(v) * 255.0f);
}

// ---- repack: quad[z][y][x] = u8x4 {v(z,y,x), v(z,y+1,x), v(z+1,y,x), v(z+1,y+1,x)} ----
// One thread per 4 consecutive x. Also zeroes the compaction counter.
__global__ __launch_bounds__(256) void repack_quad_kernel(
    const float* __restrict__ g, uint32_t* __restrict__ quad, int* __restrict__ counter)
{
    if (blockIdx.x == 0 && threadIdx.x == 0) *counter = 0;
    int t = blockIdx.x * blockDim.x + threadIdx.x;     // [0, 256*256*64)
    int x4 = (t & 63) << 2;
    int zy = t >> 6;
    int z = zy >> 8;
    int y = zy & 255;
    int yp = (y == 255) ? y : y + 1;                   // clamped rows: values unused by march
    int zp = (z == 255) ? z : z + 1;
    float4 a = *(const float4*)(g + ((z  << 16) + (y  << 8) + x4));   // (z,  y )
    float4 b = *(const float4*)(g + ((z  << 16) + (yp << 8) + x4));   // (z,  y+1)
    float4 c = *(const float4*)(g + ((zp << 16) + (y  << 8) + x4));   // (z+1,y )
    float4 d = *(const float4*)(g + ((zp << 16) + (yp << 8) + x4));   // (z+1,y+1)
    uint4 o;
    o.x = q255(a.x) | (q255(b.x) << 8) | (q255(c.x) << 16) | (q255(d.x) << 24);
    o.y = q255(a.y) | (q255(b.y) << 8) | (q255(c.y) << 16) | (q255(d.y) << 24);
    o.z = q255(a.z) | (q255(b.z) << 8) | (q255(c.z) << 16) | (q255(d.z) << 24);
    o.w = q255(a.w) | (q255(b.w) << 8) | (q255(c.w) << 16) | (q255(d.w) << 24);
    *(uint4*)(quad + ((zy << 8) + x4)) = o;
}

// ---------------- setup: slab test + wave-ballot compaction ----------------
__global__ __launch_bounds__(256) void setup_kernel(
    const float* __restrict__ rays, float* __restrict__ out,
    float* __restrict__ compactF, int* __restrict__ compactI,
    int* __restrict__ counter, int n_rays)
{
    int ray = blockIdx.x * blockDim.x + threadIdx.x;
    bool valid = false;
    float ox = 0, oy = 0, oz = 0, dx = 0, dy = 0, dz = 0, tmin = 0, seg = 0;

    if (ray < n_rays) {
        const float* r = rays + ray * 6;
        ox = r[0]; oy = r[1]; oz = r[2];
        dx = r[3]; dy = r[4]; dz = r[5];
        float nrm = sqrtf(dx*dx + dy*dy + dz*dz) + REF_EPS;
        float inv_n = 1.0f / nrm;
        dx *= inv_n; dy *= inv_n; dz *= inv_n;
        float ixv = safe_inv(dx), iyv = safe_inv(dy), izv = safe_inv(dz);
        float tax = (-1.0f - ox) * ixv, tbx = (1.0f - ox) * ixv;
        float tay = (-1.0f - oy) * iyv, tby = (1.0f - oy) * iyv;
        float taz = (-1.0f - oz) * izv, tbz = (1.0f - oz) * izv;
        tmin = fmaxf(fmaxf(fminf(tax, tbx), fminf(tay, tby)), fminf(taz, tbz));
        float tmax = fminf(fminf(fmaxf(tax, tbx), fmaxf(tay, tby)), fmaxf(taz, tbz));
        tmin = fmaxf(tmin, 0.0f);
        valid = tmax > tmin;
        seg = valid ? (tmax - tmin) : 0.0f;
    }

    unsigned long long mask = __ballot(valid);
    int lane = threadIdx.x & 63;
    int nbefore = __popcll(mask & ((1ull << lane) - 1ull));
    int total = __popcll(mask);
    int base = 0;
    if (lane == 0) base = atomicAdd(counter, total);
    base = __shfl(base, 0);

    if (valid) {
        int idx = base + nbefore;
        float4* dst = (float4*)(compactF + (size_t)idx * 8);
        dst[0] = make_float4(ox, oy, oz, dx);
        dst[1] = make_float4(dy, dz, tmin, seg);
        compactI[idx] = ray;
    } else if (ray < n_rays) {
        out[ray] = 1.0f;
    }
}

// -------- march: 8 threads/ray, grid-stride over compact rays, u8 quad grid --------
__global__ __launch_bounds__(256) void march_kernel(
    const float* __restrict__ compactF, const int* __restrict__ compactI,
    const int* __restrict__ counter, const uint32_t* __restrict__ quad,
    float* __restrict__ out)
{
    int gid = blockIdx.x * blockDim.x + threadIdx.x;
    int sub = gid & 7;
    int nvalid = *counter;
    int stride = (gridDim.x * blockDim.x) >> 3;

    for (int ray = gid >> 3; ray < nvalid; ray += stride) {
        const float4* c = (const float4*)(compactF + (size_t)ray * 8);
        float4 c0 = c[0], c1 = c[1];
        float ox = c0.x, oy = c0.y, oz = c0.z;
        float dx = c0.w, dy = c1.x, dz = c1.y;
        float tmin = c1.z, seg = c1.w;

        float sum = 0.0f;
        #pragma unroll 4
        for (int i = sub; i < N_STEPS; i += 8) {
            float frac = ((float)i + 0.5f) * (1.0f / (float)N_STEPS);
            float t = fmaf(seg, frac, tmin);
            float px = fmaf(t, dx, ox);
            float py = fmaf(t, dy, oy);
            float pz = fmaf(t, dz, oz);
            float gx = (px + 1.0f) * (0.5f * 255.0f);
            float gy = (py + 1.0f) * (0.5f * 255.0f);
            float gz = (pz + 1.0f) * (0.5f * 255.0f);

            float fx0 = floorf(gx), fy0 = floorf(gy), fz0 = floorf(gz);
            int x0 = (int)fminf(fmaxf(fx0, 0.0f), 254.0f);
            int y0 = (int)fminf(fmaxf(fy0, 0.0f), 254.0f);
            int z0 = (int)fminf(fmaxf(fz0, 0.0f), 254.0f);
            float fx = fminf(fmaxf(gx - (float)x0, 0.0f), 1.0f);
            float fy = fminf(fmaxf(gy - (float)y0, 0.0f), 1.0f);
            float fz = fminf(fmaxf(gz - (float)z0, 0.0f), 1.0f);

            int vidx = (z0 << 16) + (y0 << 8) + x0;
            uint2 v = *(const uint2_a4*)(quad + vidx);
            // v.x bytes: c000,c010,c100,c110 ; v.y bytes: c001,c011,c101,c111
            float c000 = (float)( v.x        & 0xffu);
            float c010 = (float)((v.x >>  8) & 0xffu);
            float c100 = (float)((v.x >> 16) & 0xffu);
            float c110 = (float)( v.x >> 24        );
            float c001 = (float)( v.y        & 0xffu);
            float c011 = (float)((v.y >>  8) & 0xffu);
            float c101 = (float)((v.y >> 16) & 0xffu);
            float c111 = (float)( v.y >> 24        );

            float omfx = 1.0f - fx;
            float c00 = c000 * omfx + c001 * fx;
            float c01 = c010 * omfx + c011 * fx;
            float c10 = c100 * omfx + c101 * fx;
            float c11 = c110 * omfx + c111 * fx;
            float omfy = 1.0f - fy;
            float cc0 = c00 * omfy + c01 * fy;
            float cc1 = c10 * omfy + c11 * fy;
            sum += cc0 * (1.0f - fz) + cc1 * fz;   // scaled by 255
        }

        sum += __shfl_xor(sum, 1);
        sum += __shfl_xor(sum, 2);
        sum += __shfl_xor(sum, 4);

        if (sub == 0) {
            float dt = seg * (1.0f / (float)N_STEPS);
            float tau = (DENSITY_SCALE / 255.0f) * sum * dt;
            out[compactI[ray]] = expf(-tau);
        }
    }
}

// ---------------- fallback: fp16 flat grid, 8 threads per ray (round-2) -----
__global__ __launch_bounds__(256) void repack_kernel(
    const float* __restrict__ g, __half* __restrict__ gh, int n)
{
    int i = (blockIdx.x * blockDim.x + threadIdx.x) * 4;
    if (i >= n) return;
    float4 v = *(const float4*)(g + i);
    __half2* dst = (__half2*)(gh + i);
    dst[0] = __floats2half2_rn(clip01(v.x), clip01(v.y));
    dst[1] = __floats2half2_rn(clip01(v.z), clip01(v.w));
}

__global__ __launch_bounds__(256) void transmittance_h_kernel(
    const float* __restrict__ rays, const __half* __restrict__ gh,
    float* __restrict__ out, int n_rays)
{
    int gid = blockIdx.x * blockDim.x + threadIdx.x;
    int ray = gid >> 3;
    int sub = gid & 7;
    if (ray >= n_rays) return;

    const float* r = rays + ray * 6;
    float ox = r[0], oy = r[1], oz = r[2];
    float dx = r[3], dy = r[4], dz = r[5];
    float nrm = sqrtf(dx*dx + dy*dy + dz*dz) + REF_EPS;
    float inv_n = 1.0f / nrm;
    dx *= inv_n; dy *= inv_n; dz *= inv_n;
    float ixv = safe_inv(dx), iyv = safe_inv(dy), izv = safe_inv(dz);
    float tax = (-1.0f - ox) * ixv, tbx = (1.0f - ox) * ixv;
    float tay = (-1.0f - oy) * iyv, tby = (1.0f - oy) * iyv;
    float taz = (-1.0f - oz) * izv, tbz = (1.0f - oz) * izv;
    float tmin = fmaxf(fmaxf(fminf(tax, tbx), fminf(tay, tby)), fminf(taz, tbz));
    float tmax = fminf(fminf(fmaxf(tax, tbx), fmaxf(tay, tby)), fmaxf(taz, tbz));
    tmin = fmaxf(tmin, 0.0f);
    bool valid = tmax > tmin;
    float seg = valid ? (tmax - tmin) : 0.0f;
    float sum = 0.0f;

    if (valid) {
        #pragma unroll 4
        for (int i = sub; i < N_STEPS; i += 8) {
            float frac = ((float)i + 0.5f) * (1.0f / (float)N_STEPS);
            float t = fmaf(seg, frac, tmin);
            float px = fmaf(t, dx, ox);
            float py = fmaf(t, dy, oy);
            float pz = fmaf(t, dz, oz);
            float gx = (px + 1.0f) * (0.5f * 255.0f);
            float gy = (py + 1.0f) * (0.5f * 255.0f);
            float gz = (pz + 1.0f) * (0.5f * 255.0f);
            float fx0 = floorf(gx), fy0 = floorf(gy), fz0 = floorf(gz);
            int x0 = (int)fminf(fmaxf(fx0, 0.0f), 254.0f);
            int y0 = (int)fminf(fmaxf(fy0, 0.0f), 254.0f);
            int z0 = (int)fminf(fmaxf(fz0, 0.0f), 254.0f);
            float fx = fminf(fmaxf(gx - (float)x0, 0.0f), 1.0f);
            float fy = fminf(fmaxf(gy - (float)y0, 0.0f), 1.0f);
            float fz = fminf(fmaxf(gz - (float)z0, 0.0f), 1.0f);
            const __half* p0 = gh + ((z0 << 16) + (y0 << 8) + x0);
            u32_a2 a00 = *(const u32_a2*)(const void*)(p0);
            u32_a2 a01 = *(const u32_a2*)(const void*)(p0 + 256);
            u32_a2 a10 = *(const u32_a2*)(const void*)(p0 + 65536);
            u32_a2 a11 = *(const u32_a2*)(const void*)(p0 + 65536 + 256);
            float2 f00 = __half22float2(*(__half2*)&a00);
            float2 f01 = __half22float2(*(__half2*)&a01);
            float2 f10 = __half22float2(*(__half2*)&a10);
            float2 f11 = __half22float2(*(__half2*)&a11);
            float omfx = 1.0f - fx;
            float c00 = f00.x * omfx + f00.y * fx;
            float c01 = f01.x * omfx + f01.y * fx;
            float c10 = f10.x * omfx + f10.y * fx;
            float c11 = f11.x * omfx + f11.y * fx;
            float omfy = 1.0f - fy;
            float cc0 = c00 * omfy + c01 * fy;
            float cc1 = c10 * omfy + c11 * fy;
            sum += cc0 * (1.0f - fz) + cc1 * fz;
        }
    }

    sum += __shfl_xor(sum, 1);
    sum += __shfl_xor(sum, 2);
    sum += __shfl_xor(sum, 4);

    if (sub == 0) {
        float result = 1.0f;
        if (valid) {
            float dt = seg * (1.0f / (float)N_STEPS);
            float tau = DENSITY_SCALE * sum * dt;
            result = expf(-tau);
        }
        out[ray] = result;
    }
}

// ---------------- fallback: fp32 grid, 4 threads per ray (round-1) ----------
__global__ __launch_bounds__(256) void transmittance_kernel(
    const float* __restrict__ rays, const float* __restrict__ grid,
    float* __restrict__ out, int n_rays)
{
    int gid = blockIdx.x * blockDim.x + threadIdx.x;
    int ray = gid >> 2;
    int sub = gid & 3;
    if (ray >= n_rays) return;
    const float* r = rays + ray * 6;
    float ox = r[0], oy = r[1], oz = r[2];
    float dx = r[3], dy = r[4], dz = r[5];
    float nrm = sqrtf(dx*dx + dy*dy + dz*dz) + REF_EPS;
    float inv_n = 1.0f / nrm;
    dx *= inv_n; dy *= inv_n; dz *= inv_n;
    float ixv = safe_inv(dx), iyv = safe_inv(dy), izv = safe_inv(dz);
    float tax = (-1.0f - ox) * ixv, tbx = (1.0f - ox) * ixv;
    float tay = (-1.0f - oy) * iyv, tby = (1.0f - oy) * iyv;
    float taz = (-1.0f - oz) * izv, tbz = (1.0f - oz) * izv;
    float tmin = fmaxf(fmaxf(fminf(tax, tbx), fminf(tay, tby)), fminf(taz, tbz));
    float tmax = fminf(fminf(fmaxf(tax, tbx), fmaxf(tay, tby)), fmaxf(taz, tbz));
    tmin = fmaxf(tmin, 0.0f);
    bool valid = tmax > tmin;
    float result = 1.0f;
    float seg = valid ? (tmax - tmin) : 0.0f;
    float sum = 0.0f;
    if (valid) {
        #pragma unroll 4
        for (int i = sub; i < N_STEPS; i += 4) {
            float frac = ((float)i + 0.5f) * (1.0f / (float)N_STEPS);
            float t = fmaf(seg, frac, tmin);
            float px = fmaf(t, dx, ox);
            float py = fmaf(t, dy, oy);
            float pz = fmaf(t, dz, oz);
            float gx = (px + 1.0f) * (0.5f * 255.0f);
            float gy = (py + 1.0f) * (0.5f * 255.0f);
            float gz = (pz + 1.0f) * (0.5f * 255.0f);
            float fx0 = floorf(gx), fy0 = floorf(gy), fz0 = floorf(gz);
            int x0 = (int)fminf(fmaxf(fx0, 0.0f), 254.0f);
            int y0 = (int)fminf(fmaxf(fy0, 0.0f), 254.0f);
            int z0 = (int)fminf(fmaxf(fz0, 0.0f), 254.0f);
            float fx = fminf(fmaxf(gx - (float)x0, 0.0f), 1.0f);
            float fy = fminf(fmaxf(gy - (float)y0, 0.0f), 1.0f);
            float fz = fminf(fmaxf(gz - (float)z0, 0.0f), 1.0f);
            const float* p0 = grid + ((z0 << 16) + (y0 << 8) + x0);
            const float* p1 = p0 + 65536;
            float c000 = p0[0],   c001 = p0[1];
            float c010 = p0[256], c011 = p0[257];
            float c100 = p1[0],   c101 = p1[1];
            float c110 = p1[256], c111 = p1[257];
            float omfx = 1.0f - fx;
            float c00 = c000 * omfx + c001 * fx;
            float c01 = c010 * omfx + c011 * fx;
            float c10 = c100 * omfx + c101 * fx;
            float c11 = c110 * omfx + c111 * fx;
            float omfy = 1.0f - fy;
            float cc0 = c00 * omfy + c01 * fy;
            float cc1 = c10 * omfy + c11 * fy;
            sum += cc0 * (1.0f - fz) + cc1 * fz;
        }
    }
    sum += __shfl_xor(sum, 1);
    sum += __shfl_xor(sum, 2);
    if (valid) {
        float dt = seg * (1.0f / (float)N_STEPS);
        float tau = DENSITY_SCALE * sum * dt;
        result = expf(-tau);
    }
    if (sub == 0) out[ray] = result;
}

extern "C" void kernel_launch(void* const* d_in, const int* in_sizes, int n_in,
                              void* d_out, int out_size, void* d_ws, size_t ws_size,
                              hipStream_t stream) {
    const float* rays = (const float*)d_in[0];   // [65536, 6] fp32
    const float* grid = (const float*)d_in[1];   // [256,256,256] fp32
    float* out = (float*)d_out;
    int n_rays = in_sizes[0] / 6;
    int n_grid = in_sizes[1];                    // 16777216

    const size_t QUAD_BYTES = (size_t)n_grid * 4;          // 64 MB u8-quad grid
    const size_t CF_BYTES   = (size_t)n_rays * 8 * 4;
    const size_t CI_BYTES   = (size_t)n_rays * 4;
    const size_t need_full  = QUAD_BYTES + CF_BYTES + CI_BYTES + 256;
    const size_t need_half  = (size_t)n_grid * 2;          // 32 MB fp16 grid

    if (ws_size >= need_full) {
        uint32_t* quad    = (uint32_t*)d_ws;
        float*    compactF = (float*)((char*)d_ws + QUAD_BYTES);
        int*      compactI = (int*)((char*)d_ws + QUAD_BYTES + CF_BYTES);
        int*      counter  = (int*)((char*)d_ws + QUAD_BYTES + CF_BYTES + CI_BYTES);

        int rp_threads = n_grid / 4;
        repack_quad_kernel<<<(rp_threads + 255) / 256, 256, 0, stream>>>(grid, quad, counter);
        setup_kernel<<<(n_rays + 255) / 256, 256, 0, stream>>>(
            rays, out, compactF, compactI, counter, n_rays);
        // grid-stride persistent march: 1024 blocks = 16 waves/CU, ~nvalid ray slots
        march_kernel<<<1024, 256, 0, stream>>>(compactF, compactI, counter, quad, out);
    } else if (ws_size >= need_half) {
        __half* gh = (__half*)d_ws;
        int rp_threads = n_grid / 4;
        repack_kernel<<<(rp_threads + 255) / 256, 256, 0, stream>>>(grid, gh, n_grid);
        int total_threads = n_rays * 8;
        transmittance_h_kernel<<<(total_threads + 255) / 256, 256, 0, stream>>>(
            rays, gh, out, n_rays);
    } else {
        int total_threads = n_rays * 4;
        transmittance_kernel<<<(total_threads + 255) / 256, 256, 0, stream>>>(
            rays, grid, out, n_rays);
    }
}